// Round 8
// baseline (372.458 us; speedup 1.0000x reference)
//
#include <hip/hip_runtime.h>

#define CHN 128          // channels per row
#define HALF_CHN 64      // float2 / u32-bf16x2 per row == wave size
#define CAP_V 48         // node bucket capacity (deg_v ~ Poisson(16); P(>=48)~6e-11)
#define CAP_E 80         // edge bucket capacity (deg_e ~ Poisson(32); P(>=80)~0)

// ---- two-phase binning parameters -----------------------------------------
#define BIN_W_V 256      // node-bin width (pow2): 391 bins over N=100000
#define SH_V 8
#define BIN_W_EF 64      // edge-bin width == fused fill_e_v2e block ownership
#define SH_EF 6          // 782 bins over E=50000
#define MAXB_V 512       // LDS histogram capacity, node side
#define MAXB_E 1024      // LDS histogram capacity, edge side
#define CAP_BIN_V 4608   // entries per node-bin segment (mean 4096, +8 sigma)
#define CAP_BIN_E 2560   // entries per edge-bin segment (mean 2046, +11 sigma)
#define B1_THREADS 512
#define B1_PER_THREAD 8
#define B1_CHUNK (B1_THREADS * B1_PER_THREAD)   // 4096 entries/block

// ---------------------------------------------------------------------------
// bf16x2 pack/unpack (RNE)
// ---------------------------------------------------------------------------
__device__ __forceinline__ unsigned pack_bf16x2(float a, float b) {
    unsigned ua = __float_as_uint(a);
    unsigned ub = __float_as_uint(b);
    ua = (ua + 0x7FFFu + ((ua >> 16) & 1u)) >> 16;
    ub = (ub + 0x7FFFu + ((ub >> 16) & 1u)) >> 16;
    return ua | (ub << 16);
}
__device__ __forceinline__ float2 unpack_bf16x2(unsigned h) {
    float2 r;
    r.x = __uint_as_float(h << 16);
    r.y = __uint_as_float(h & 0xFFFF0000u);
    return r;
}

// per-lane 2-way softmax for this lane's channel pair (c = 2*lane, 2*lane+1).
__device__ __forceinline__ void lane_softmax(const float* __restrict__ lw,
                                             int lane, float2& s0, float2& s1) {
    float2 w0 = ((const float2*)lw)[lane];
    float2 w1 = ((const float2*)(lw + CHN))[lane];
    float mx = fmaxf(w0.x, w1.x), my = fmaxf(w0.y, w1.y);
    float e0x = expf(w0.x - mx), e1x = expf(w1.x - mx);
    float e0y = expf(w0.y - my), e1y = expf(w1.y - my);
    float ix = 1.0f / (e0x + e1x), iy = 1.0f / (e0y + e1y);
    s0.x = e0x * ix; s1.x = e1x * ix;
    s0.y = e0y * iy; s1.y = e1y * iy;
}

// ---------------------------------------------------------------------------
// 1) partition: bin (v,e) pairs by node range AND by edge range, u32 entries.
//    bins_v entry = (v_local:8 <<16) | e      (e < 65536)
//    bins_e entry = (e_local:6 <<17) | v      (v < 131072)
//    512 threads/block (8 waves) for latency hiding; 391 blocks.
// ---------------------------------------------------------------------------
__global__ __launch_bounds__(B1_THREADS) void partition_kernel(
    const int* __restrict__ node_idx, const int* __restrict__ edge_idx,
    int* __restrict__ gcur_v, int* __restrict__ gcur_e,
    unsigned* __restrict__ bins_v, unsigned* __restrict__ bins_e,
    int nnz, int nbv, int nbe) {
    __shared__ int hist_v[MAXB_V], cur_v[MAXB_V];
    __shared__ int hist_e[MAXB_E], cur_e[MAXB_E];
    int tid = threadIdx.x;
    for (int b = tid; b < MAXB_V; b += B1_THREADS) hist_v[b] = 0;
    for (int b = tid; b < MAXB_E; b += B1_THREADS) hist_e[b] = 0;
    __syncthreads();

    long long base = (long long)blockIdx.x * B1_CHUNK;
    int v[B1_PER_THREAD], e[B1_PER_THREAD];
    const int4* ni4 = (const int4*)node_idx;
    const int4* ei4 = (const int4*)edge_idx;
#pragma unroll
    for (int r = 0; r < B1_PER_THREAD / 4; ++r) {
        long long i4 = base / 4 + (long long)r * B1_THREADS + tid;
        if (i4 * 4 + 3 < nnz) {
            int4 a = ni4[i4];
            int4 bq = ei4[i4];
            v[r*4+0] = a.x;  v[r*4+1] = a.y;  v[r*4+2] = a.z;  v[r*4+3] = a.w;
            e[r*4+0] = bq.x; e[r*4+1] = bq.y; e[r*4+2] = bq.z; e[r*4+3] = bq.w;
        } else {
#pragma unroll
            for (int j = 0; j < 4; ++j) {
                long long i = i4 * 4 + j;
                v[r*4+j] = (i < nnz) ? node_idx[i] : -1;
                e[r*4+j] = (i < nnz) ? edge_idx[i] : -1;
            }
        }
    }
#pragma unroll
    for (int k = 0; k < B1_PER_THREAD; ++k)
        if (v[k] >= 0) {
            atomicAdd(&hist_v[(v[k] >> SH_V) & (MAXB_V - 1)], 1);
            atomicAdd(&hist_e[(e[k] >> SH_EF) & (MAXB_E - 1)], 1);
        }
    __syncthreads();
    for (int b = tid; b < nbv; b += B1_THREADS) {
        int h = hist_v[b];
        int off = h ? atomicAdd(&gcur_v[b], h) : 0;
        cur_v[b] = b * CAP_BIN_V + off;
    }
    for (int b = tid; b < nbe; b += B1_THREADS) {
        int h = hist_e[b];
        int off = h ? atomicAdd(&gcur_e[b], h) : 0;
        cur_e[b] = b * CAP_BIN_E + off;
    }
    __syncthreads();
#pragma unroll
    for (int k = 0; k < B1_PER_THREAD; ++k)
        if (v[k] >= 0) {
            int bv = (v[k] >> SH_V) & (MAXB_V - 1);
            int s = atomicAdd(&cur_v[bv], 1);
            if (s < (bv + 1) * CAP_BIN_V)
                bins_v[s] = ((unsigned)(v[k] & (BIN_W_V - 1)) << 16) | (unsigned)e[k];
            int be = (e[k] >> SH_EF) & (MAXB_E - 1);
            int t = atomicAdd(&cur_e[be], 1);
            if (t < (be + 1) * CAP_BIN_E)
                bins_e[t] = ((unsigned)(e[k] & (BIN_W_EF - 1)) << 17) | (unsigned)v[k];
        }
}

// ---------------------------------------------------------------------------
// 2) fill_v + cast fused: one block (512 thr) per node-bin (256-node range).
//    LDS-atomic slot assignment -> nbkt_t TRANSPOSED (u16, [slot][node]) so
//    the sliced e2v's per-slot loads touch only used entries. Then, with
//    final degrees in LDS, writes Xh = bf16x2(X * inv_deg_v) for its rows.
// ---------------------------------------------------------------------------
__global__ __launch_bounds__(512) void fill_v_cast_kernel(
    const unsigned* __restrict__ bins_v, const int* __restrict__ gcur_v,
    const float2* __restrict__ X2,
    int* __restrict__ cnt_v, unsigned short* __restrict__ nbkt_t,
    unsigned* __restrict__ Xh, int n_nodes) {
    __shared__ int lcnt[BIN_W_V];
    int b = blockIdx.x;
    int lo = b << SH_V;
    int hi = lo + BIN_W_V; if (hi > n_nodes) hi = n_nodes;
    int nl = hi - lo;
    for (int i = threadIdx.x; i < nl; i += 512) lcnt[i] = 0;
    __syncthreads();
    int m = gcur_v[b];
    if (m > CAP_BIN_V) m = CAP_BIN_V;
    if (m < 0) m = 0;
    const unsigned* seg = bins_v + (size_t)b * CAP_BIN_V;
    for (int i = threadIdx.x; i < m; i += 512) {
        unsigned p = seg[i];
        int vl = (int)(p >> 16) & (BIN_W_V - 1);
        int e  = (int)(p & 0xFFFFu);
        int s = atomicAdd(&lcnt[vl], 1);
        if (s < CAP_V) nbkt_t[(size_t)s * n_nodes + (lo + vl)] = (unsigned short)e;
    }
    __syncthreads();
    for (int i = threadIdx.x; i < nl; i += 512) cnt_v[lo + i] = lcnt[i];
    // fused cast for rows [lo,hi): coalesced float2 stream
    int total = nl * HALF_CHN;
    for (int i = threadIdx.x; i < total; i += 512) {
        int r = i >> 6, w = i & 63;
        int d = lcnt[r];
        float sc = (d > 0) ? 1.0f / (float)d : 0.0f;
        float2 x = X2[(size_t)(lo + r) * HALF_CHN + w];
        Xh[(size_t)(lo + r) * HALF_CHN + w] = pack_bf16x2(x.x * sc, x.y * sc);
    }
}

// ---------------------------------------------------------------------------
// 3) fill_e + v2e fused: one block (512 thr = 8 waves) per 64-edge bin.
//    Buckets built in LDS (never hit global); each wave gathers 8 edges with
//    the proven unroll-8 row-sum loop (indices via LDS broadcast).
//    Writes fp32 edge_out and GROUP-MAJOR bf16 enh[4][E][16 words] so the
//    sliced e2v's per-XCD slice (3.2 MB) is contiguous.
// ---------------------------------------------------------------------------
__global__ __launch_bounds__(512) void fill_e_v2e_kernel(
    const unsigned* __restrict__ bins_e, const int* __restrict__ gcur_e,
    const unsigned* __restrict__ Xh, const float* __restrict__ Y,
    const float* __restrict__ lw,
    float* __restrict__ edge_out, unsigned* __restrict__ enh, int n_edges) {
    __shared__ int lcnt[BIN_W_EF];
    __shared__ int bkt[BIN_W_EF][CAP_E];     // 64*80*4 = 20 KB
    int b = blockIdx.x;
    int lo = b << SH_EF;
    int hi = lo + BIN_W_EF; if (hi > n_edges) hi = n_edges;
    int nl = hi - lo;
    for (int i = threadIdx.x; i < BIN_W_EF; i += 512) lcnt[i] = 0;
    __syncthreads();
    int m = gcur_e[b];
    if (m > CAP_BIN_E) m = CAP_BIN_E;
    if (m < 0) m = 0;
    const unsigned* seg = bins_e + (size_t)b * CAP_BIN_E;
    for (int i = threadIdx.x; i < m; i += 512) {
        unsigned p = seg[i];
        int el = (int)(p >> 17) & (BIN_W_EF - 1);
        int v  = (int)(p & 0x1FFFFu);
        int s = atomicAdd(&lcnt[el], 1);
        if (s < CAP_E) bkt[el][s] = v;
    }
    __syncthreads();

    int wv = threadIdx.x >> 6, lane = threadIdx.x & 63;
    float2 s0, s1;
    lane_softmax(lw, lane, s0, s1);
    int eg = lane >> 4, ew = lane & 15;     // group / word-in-group for enh

    for (int me = wv; me < nl; me += 8) {
        int edge = lo + me;
        int deg_raw = lcnt[me];                 // wave-uniform (LDS broadcast)
        int deg = deg_raw > CAP_E ? CAP_E : deg_raw;
        const int* bk = bkt[me];
        float2 a0 = {0.f,0.f}, a1 = {0.f,0.f}, a2 = {0.f,0.f}, a3 = {0.f,0.f};
        int k = 0;
        for (; k + 8 <= deg; k += 8) {
            int i0 = bk[k+0], i1 = bk[k+1], i2 = bk[k+2], i3 = bk[k+3];
            int i4 = bk[k+4], i5 = bk[k+5], i6 = bk[k+6], i7 = bk[k+7];
            unsigned h0 = Xh[(size_t)i0 * HALF_CHN + lane];
            unsigned h1 = Xh[(size_t)i1 * HALF_CHN + lane];
            unsigned h2 = Xh[(size_t)i2 * HALF_CHN + lane];
            unsigned h3 = Xh[(size_t)i3 * HALF_CHN + lane];
            unsigned h4 = Xh[(size_t)i4 * HALF_CHN + lane];
            unsigned h5 = Xh[(size_t)i5 * HALF_CHN + lane];
            unsigned h6 = Xh[(size_t)i6 * HALF_CHN + lane];
            unsigned h7 = Xh[(size_t)i7 * HALF_CHN + lane];
            float2 x0 = unpack_bf16x2(h0), x1 = unpack_bf16x2(h1);
            float2 x2 = unpack_bf16x2(h2), x3 = unpack_bf16x2(h3);
            float2 x4 = unpack_bf16x2(h4), x5 = unpack_bf16x2(h5);
            float2 x6 = unpack_bf16x2(h6), x7 = unpack_bf16x2(h7);
            a0.x += x0.x; a0.y += x0.y;  a1.x += x1.x; a1.y += x1.y;
            a2.x += x2.x; a2.y += x2.y;  a3.x += x3.x; a3.y += x3.y;
            a0.x += x4.x; a0.y += x4.y;  a1.x += x5.x; a1.y += x5.y;
            a2.x += x6.x; a2.y += x6.y;  a3.x += x7.x; a3.y += x7.y;
        }
        for (; k < deg; ++k) {
            float2 x = unpack_bf16x2(Xh[(size_t)bk[k] * HALF_CHN + lane]);
            a0.x += x.x; a0.y += x.y;
        }
        float2 acc;
        acc.x = (a0.x + a1.x) + (a2.x + a3.x);
        acc.y = (a0.y + a1.y) + (a2.y + a3.y);
        float2 y = ((const float2*)Y)[(size_t)edge * HALF_CHN + lane];
        float2 ef;
        ef.x = s0.x * acc.x + s1.x * y.x;
        ef.y = s0.y * acc.y + s1.y * y.y;
        ((float2*)edge_out)[(size_t)edge * HALF_CHN + lane] = ef;
        float we = (deg_raw > 0) ? 1.0f / (float)deg_raw : 0.0f;
        enh[((size_t)eg * n_edges + edge) * 16 + ew] = pack_bf16x2(ef.x * we, ef.y * we);
    }
}

// ---------------------------------------------------------------------------
// 4) e2v gather, 4-way XCD-sliced: block = (16-node chunk, group g=blockIdx&3).
//    Each XCD caches one 3.2 MB enh slice (L2-resident). Wave owns 4 nodes
//    sequentially; per node, ladder of 4-slot blocks (deg wave-uniform,
//    Poisson(16) -> 1.5 blocks avg), 4 idx loads + 4 gathers issued together
//    for MLP. sub = lane>>4 covers slots, wi = lane&15 covers 32 channels.
// ---------------------------------------------------------------------------
__global__ __launch_bounds__(256, 4) void e2v_kernel(
    const float* __restrict__ X, const unsigned* __restrict__ enh,
    const int* __restrict__ cnt_v, const unsigned short* __restrict__ nbkt_t,
    const float* __restrict__ lw,
    float* __restrict__ node_out, int n_nodes, int n_edges) {
    int g     = blockIdx.x & 3;
    int chunk = blockIdx.x >> 2;
    int wv    = threadIdx.x >> 6;
    int lane  = threadIdx.x & 63;
    int sub   = lane >> 4;
    int wi    = lane & 15;
    int c2    = (g << 4) + wi;             // float2 channel pair 0..63
    // per-lane softmax for channel pair c2
    float2 w0 = ((const float2*)lw)[c2];
    float2 w1 = ((const float2*)(lw + CHN))[c2];
    float mx = fmaxf(w0.x, w1.x), my = fmaxf(w0.y, w1.y);
    float e0x = expf(w0.x - mx), e1x = expf(w1.x - mx);
    float e0y = expf(w0.y - my), e1y = expf(w1.y - my);
    float ix = 1.0f / (e0x + e1x), iy = 1.0f / (e0y + e1y);
    float s0x = e0x * ix, s1x = e1x * ix;
    float s0y = e0y * iy, s1y = e1y * iy;

    const size_t gbase = (size_t)g * (size_t)n_edges * 16;
    int node0 = chunk * 16 + wv * 4;
#pragma unroll
    for (int t = 0; t < 4; ++t) {
        int node = node0 + t;
        if (node >= n_nodes) break;        // wave-uniform
        int deg = cnt_v[node];
        if (deg > CAP_V) deg = CAP_V;
        float2 acc = {0.f, 0.f};
#define DO_BLK(B)                                                              \
        {                                                                      \
            int j0 = (B) + sub, j1 = j0 + 4, j2 = j0 + 8, j3 = j0 + 12;        \
            int i0 = (int)nbkt_t[(size_t)j0 * n_nodes + node];                 \
            int i1 = (int)nbkt_t[(size_t)j1 * n_nodes + node];                 \
            int i2 = (int)nbkt_t[(size_t)j2 * n_nodes + node];                 \
            int i3 = (int)nbkt_t[(size_t)j3 * n_nodes + node];                 \
            if (j0 >= deg) i0 = 0;                                             \
            if (j1 >= deg) i1 = 0;                                             \
            if (j2 >= deg) i2 = 0;                                             \
            if (j3 >= deg) i3 = 0;                                             \
            unsigned h0 = enh[gbase + (size_t)i0 * 16 + wi];                   \
            unsigned h1 = enh[gbase + (size_t)i1 * 16 + wi];                   \
            unsigned h2 = enh[gbase + (size_t)i2 * 16 + wi];                   \
            unsigned h3 = enh[gbase + (size_t)i3 * 16 + wi];                   \
            float2 x0 = unpack_bf16x2(h0), x1 = unpack_bf16x2(h1);             \
            float2 x2 = unpack_bf16x2(h2), x3 = unpack_bf16x2(h3);             \
            if (j0 < deg) { acc.x += x0.x; acc.y += x0.y; }                    \
            if (j1 < deg) { acc.x += x1.x; acc.y += x1.y; }                    \
            if (j2 < deg) { acc.x += x2.x; acc.y += x2.y; }                    \
            if (j3 < deg) { acc.x += x3.x; acc.y += x3.y; }                    \
        }
        if (deg > 0)  DO_BLK(0)
        if (deg > 16) DO_BLK(16)
        if (deg > 32) DO_BLK(32)
#undef DO_BLK
        // reduce across the 4 sub slots (lane bits 4,5)
        acc.x += __shfl_xor(acc.x, 16, 64);
        acc.y += __shfl_xor(acc.y, 16, 64);
        acc.x += __shfl_xor(acc.x, 32, 64);
        acc.y += __shfl_xor(acc.y, 32, 64);
        float2 x = ((const float2*)X)[(size_t)node * HALF_CHN + c2];
        float2 nf;
        nf.x = s0x * acc.x + s1x * x.x;
        nf.y = s0y * acc.y + s1y * x.y;
        if (sub == 0)
            ((float2*)node_out)[(size_t)node * HALF_CHN + c2] = nf;
    }
}

// ---------------------------------------------------------------------------
extern "C" void kernel_launch(void* const* d_in, const int* in_sizes, int n_in,
                              void* d_out, int out_size, void* d_ws, size_t ws_size,
                              hipStream_t stream) {
    const float* X  = (const float*)d_in[0];
    const float* Y  = (const float*)d_in[1];
    const float* lw = (const float*)d_in[2];
    const int* node_idx = (const int*)d_in[3];
    const int* edge_idx = (const int*)d_in[4];

    const int N   = in_sizes[0] / CHN;   // 100000
    const int E   = in_sizes[1] / CHN;   // 50000
    const int nnz = in_sizes[3];         // 1600000

    float* node_out = (float*)d_out;                    // [N, C]  [0, 51.2 MB)
    float* edge_out = (float*)d_out + (size_t)N * CHN;  // [E, C]  [51.2, 76.8 MB)

    const int nbv = (N + BIN_W_V - 1) >> SH_V;    // 391
    const int nbe = (E + BIN_W_EF - 1) >> SH_EF;  // 782

    // Dead-region reuse inside node_out's 51.2 MB (all dead before e2v writes):
    //   [0, 25.6 MB)     Xh     : N*64 u32 bf16x2 rows
    //   [25.6, ~40.8 MB) bins_v ++ bins_e : u32 packed pair segments
    unsigned* Xh = (unsigned*)d_out;
    unsigned* bins_v = (unsigned*)((char*)d_out + (size_t)N * HALF_CHN * 4);
    unsigned* bins_e = bins_v + (size_t)nbv * CAP_BIN_V;

    // --- workspace carve-out (256B aligned) ---
    char* p = (char*)d_ws;
    auto carve = [&](size_t bytes) {
        char* r = p;
        p += (bytes + 255) & ~(size_t)255;
        return r;
    };
    int* cnt    = (int*)carve((size_t)(N + MAXB_V + MAXB_E) * 4);
    int* cnt_v  = cnt;
    int* gcur_v = cnt + N;
    int* gcur_e = gcur_v + MAXB_V;
    unsigned short* nbkt_t = (unsigned short*)carve((size_t)N * CAP_V * 2);  // 9.6 MB
    unsigned* enh = (unsigned*)carve((size_t)E * HALF_CHN * 4);              // 12.8 MB
    (void)ws_size;

    // 1) zero degree counters + bin cursors (ws is poisoned before every call)
    hipMemsetAsync(cnt, 0, (size_t)(N + MAXB_V + MAXB_E) * 4, stream);

    // 2) partition into per-range u32 bins (block-aggregated reservations)
    {
        int nblk = (int)((nnz + B1_CHUNK - 1) / B1_CHUNK);
        partition_kernel<<<nblk, B1_THREADS, 0, stream>>>(
            node_idx, edge_idx, gcur_v, gcur_e, bins_v, bins_e, nnz, nbv, nbe);
    }

    // 3) fill node buckets (transposed) + fused Xh cast
    fill_v_cast_kernel<<<nbv, 512, 0, stream>>>(
        bins_v, gcur_v, (const float2*)X, cnt_v, nbkt_t, Xh, N);

    // 4) fused fill_e + v2e (LDS buckets; enh group-major)
    fill_e_v2e_kernel<<<nbe, 512, 0, stream>>>(
        bins_e, gcur_e, Xh, Y, lw, edge_out, enh, E);

    // 5) sliced e2v gather -> node_out (overwrites dead Xh/bins region)
    {
        int nblk = ((N + 15) / 16) * 4;
        e2v_kernel<<<nblk, 256, 0, stream>>>(
            X, enh, cnt_v, nbkt_t, lw, node_out, N, E);
    }
}

// Round 9
// 315.356 us; speedup vs baseline: 1.1811x; 1.1811x over previous
//
#include <hip/hip_runtime.h>

#define CHN 128          // channels per row
#define HALF_CHN 64      // float2 / u32-bf16x2 per row == wave size
#define CAP_V 48         // node bucket capacity (deg_v ~ Poisson(16); P(>=48)~6e-11)
#define CAP_E 80         // edge bucket capacity (deg_e ~ Poisson(32); P(>=80)~0)

// ---- binning parameters ----------------------------------------------------
#define BIN_W_V 128      // node-bin width == e2v_fused block ownership (782 bins)
#define SH_V 7
#define BIN_W_EF 64      // edge-bin width == fill_e_v2e block ownership (782 bins)
#define SH_EF 6
#define MAXB 1024        // LDS histogram capacity per side
#define CAP_BIN_V 2560   // entries per node-bin segment (mean 2048, +11 sigma)
#define CAP_BIN_E 2560   // entries per edge-bin segment (mean 2046, +11 sigma)
#define B1_THREADS 512
#define B1_PER_THREAD 8
#define B1_CHUNK (B1_THREADS * B1_PER_THREAD)   // 4096 entries/block

// ---------------------------------------------------------------------------
// bf16x2 pack/unpack (RNE)
// ---------------------------------------------------------------------------
__device__ __forceinline__ unsigned pack_bf16x2(float a, float b) {
    unsigned ua = __float_as_uint(a);
    unsigned ub = __float_as_uint(b);
    ua = (ua + 0x7FFFu + ((ua >> 16) & 1u)) >> 16;
    ub = (ub + 0x7FFFu + ((ub >> 16) & 1u)) >> 16;
    return ua | (ub << 16);
}
__device__ __forceinline__ float2 unpack_bf16x2(unsigned h) {
    float2 r;
    r.x = __uint_as_float(h << 16);
    r.y = __uint_as_float(h & 0xFFFF0000u);
    return r;
}

// per-lane 2-way softmax for this lane's channel pair (c = 2*lane, 2*lane+1).
__device__ __forceinline__ void lane_softmax(const float* __restrict__ lw,
                                             int lane, float2& s0, float2& s1) {
    float2 w0 = ((const float2*)lw)[lane];
    float2 w1 = ((const float2*)(lw + CHN))[lane];
    float mx = fmaxf(w0.x, w1.x), my = fmaxf(w0.y, w1.y);
    float e0x = expf(w0.x - mx), e1x = expf(w1.x - mx);
    float e0y = expf(w0.y - my), e1y = expf(w1.y - my);
    float ix = 1.0f / (e0x + e1x), iy = 1.0f / (e0y + e1y);
    s0.x = e0x * ix; s1.x = e1x * ix;
    s0.y = e0y * iy; s1.y = e1y * iy;
}

// ---------------------------------------------------------------------------
// 1) partition: bin (v,e) pairs by node range AND by edge range, u32 entries.
//    bins_v entry = (v_local:7 <<16) | e      (e < 65536)
//    bins_e entry = (e_local:6 <<17) | v      (v < 131072)
//    512 threads/block (8 waves); 391 blocks. Block-aggregated reservations.
// ---------------------------------------------------------------------------
__global__ __launch_bounds__(B1_THREADS) void partition_kernel(
    const int* __restrict__ node_idx, const int* __restrict__ edge_idx,
    int* __restrict__ gcur_v, int* __restrict__ gcur_e,
    unsigned* __restrict__ bins_v, unsigned* __restrict__ bins_e,
    int nnz, int nbv, int nbe) {
    __shared__ int hist_v[MAXB], cur_v[MAXB];
    __shared__ int hist_e[MAXB], cur_e[MAXB];
    int tid = threadIdx.x;
    for (int b = tid; b < MAXB; b += B1_THREADS) { hist_v[b] = 0; hist_e[b] = 0; }
    __syncthreads();

    long long base = (long long)blockIdx.x * B1_CHUNK;
    int v[B1_PER_THREAD], e[B1_PER_THREAD];
    const int4* ni4 = (const int4*)node_idx;
    const int4* ei4 = (const int4*)edge_idx;
#pragma unroll
    for (int r = 0; r < B1_PER_THREAD / 4; ++r) {
        long long i4 = base / 4 + (long long)r * B1_THREADS + tid;
        if (i4 * 4 + 3 < nnz) {
            int4 a = ni4[i4];
            int4 bq = ei4[i4];
            v[r*4+0] = a.x;  v[r*4+1] = a.y;  v[r*4+2] = a.z;  v[r*4+3] = a.w;
            e[r*4+0] = bq.x; e[r*4+1] = bq.y; e[r*4+2] = bq.z; e[r*4+3] = bq.w;
        } else {
#pragma unroll
            for (int j = 0; j < 4; ++j) {
                long long i = i4 * 4 + j;
                v[r*4+j] = (i < nnz) ? node_idx[i] : -1;
                e[r*4+j] = (i < nnz) ? edge_idx[i] : -1;
            }
        }
    }
#pragma unroll
    for (int k = 0; k < B1_PER_THREAD; ++k)
        if (v[k] >= 0) {
            atomicAdd(&hist_v[(v[k] >> SH_V) & (MAXB - 1)], 1);
            atomicAdd(&hist_e[(e[k] >> SH_EF) & (MAXB - 1)], 1);
        }
    __syncthreads();
    for (int b = tid; b < nbv; b += B1_THREADS) {
        int h = hist_v[b];
        int off = h ? atomicAdd(&gcur_v[b], h) : 0;
        cur_v[b] = b * CAP_BIN_V + off;
    }
    for (int b = tid; b < nbe; b += B1_THREADS) {
        int h = hist_e[b];
        int off = h ? atomicAdd(&gcur_e[b], h) : 0;
        cur_e[b] = b * CAP_BIN_E + off;
    }
    __syncthreads();
#pragma unroll
    for (int k = 0; k < B1_PER_THREAD; ++k)
        if (v[k] >= 0) {
            int bv = (v[k] >> SH_V) & (MAXB - 1);
            int s = atomicAdd(&cur_v[bv], 1);
            if (s < (bv + 1) * CAP_BIN_V)
                bins_v[s] = ((unsigned)(v[k] & (BIN_W_V - 1)) << 16) | (unsigned)e[k];
            int be = (e[k] >> SH_EF) & (MAXB - 1);
            int t = atomicAdd(&cur_e[be], 1);
            if (t < (be + 1) * CAP_BIN_E)
                bins_e[t] = ((unsigned)(e[k] & (BIN_W_EF - 1)) << 17) | (unsigned)v[k];
        }
}

// ---------------------------------------------------------------------------
// 2) count_v + cast: one block (512 thr) per 128-node bin. LDS histogram of
//    node degrees (NO bucket stores — buckets are rebuilt in LDS by e2v),
//    then writes Xh = bf16x2(X * inv_deg_v) for its rows. No global cnt_v.
// ---------------------------------------------------------------------------
__global__ __launch_bounds__(512) void count_v_cast_kernel(
    const unsigned* __restrict__ bins_v, const int* __restrict__ gcur_v,
    const float2* __restrict__ X2,
    unsigned* __restrict__ Xh, int n_nodes) {
    __shared__ int lcnt[BIN_W_V];
    int b = blockIdx.x;
    int lo = b << SH_V;
    int hi = lo + BIN_W_V; if (hi > n_nodes) hi = n_nodes;
    int nl = hi - lo;
    for (int i = threadIdx.x; i < nl; i += 512) lcnt[i] = 0;
    __syncthreads();
    int m = gcur_v[b];
    if (m > CAP_BIN_V) m = CAP_BIN_V;
    if (m < 0) m = 0;
    const unsigned* seg = bins_v + (size_t)b * CAP_BIN_V;
    for (int i = threadIdx.x; i < m; i += 512)
        atomicAdd(&lcnt[(int)(seg[i] >> 16) & (BIN_W_V - 1)], 1);
    __syncthreads();
    int total = nl * HALF_CHN;
    for (int i = threadIdx.x; i < total; i += 512) {
        int r = i >> 6, w = i & 63;
        int d = lcnt[r];
        float sc = (d > 0) ? 1.0f / (float)d : 0.0f;
        float2 x = X2[(size_t)(lo + r) * HALF_CHN + w];
        Xh[(size_t)(lo + r) * HALF_CHN + w] = pack_bf16x2(x.x * sc, x.y * sc);
    }
}

// ---------------------------------------------------------------------------
// 3) fill_e + v2e fused (round-7 proven form): one block (512 thr = 8 waves)
//    per 64-edge bin. Buckets built in LDS; each wave gathers 8 edges with
//    the unroll-8 row-sum loop. Writes fp32 edge_out and ROW-MAJOR bf16 enh.
// ---------------------------------------------------------------------------
__global__ __launch_bounds__(512) void fill_e_v2e_kernel(
    const unsigned* __restrict__ bins_e, const int* __restrict__ gcur_e,
    const unsigned* __restrict__ Xh, const float* __restrict__ Y,
    const float* __restrict__ lw,
    float* __restrict__ edge_out, unsigned* __restrict__ enh, int n_edges) {
    __shared__ int lcnt[BIN_W_EF];
    __shared__ int bkt[BIN_W_EF][CAP_E];     // 64*80*4 = 20 KB
    int b = blockIdx.x;
    int lo = b << SH_EF;
    int hi = lo + BIN_W_EF; if (hi > n_edges) hi = n_edges;
    int nl = hi - lo;
    for (int i = threadIdx.x; i < BIN_W_EF; i += 512) lcnt[i] = 0;
    __syncthreads();
    int m = gcur_e[b];
    if (m > CAP_BIN_E) m = CAP_BIN_E;
    if (m < 0) m = 0;
    const unsigned* seg = bins_e + (size_t)b * CAP_BIN_E;
    for (int i = threadIdx.x; i < m; i += 512) {
        unsigned p = seg[i];
        int el = (int)(p >> 17) & (BIN_W_EF - 1);
        int v  = (int)(p & 0x1FFFFu);
        int s = atomicAdd(&lcnt[el], 1);
        if (s < CAP_E) bkt[el][s] = v;
    }
    __syncthreads();

    int wv = threadIdx.x >> 6, lane = threadIdx.x & 63;
    float2 s0, s1;
    lane_softmax(lw, lane, s0, s1);

    for (int me = wv; me < nl; me += 8) {
        int edge = lo + me;
        int deg_raw = lcnt[me];                 // wave-uniform (LDS broadcast)
        int deg = deg_raw > CAP_E ? CAP_E : deg_raw;
        const int* bk = bkt[me];
        float2 a0 = {0.f,0.f}, a1 = {0.f,0.f}, a2 = {0.f,0.f}, a3 = {0.f,0.f};
        int k = 0;
        for (; k + 8 <= deg; k += 8) {
            int i0 = bk[k+0], i1 = bk[k+1], i2 = bk[k+2], i3 = bk[k+3];
            int i4 = bk[k+4], i5 = bk[k+5], i6 = bk[k+6], i7 = bk[k+7];
            unsigned h0 = Xh[(size_t)i0 * HALF_CHN + lane];
            unsigned h1 = Xh[(size_t)i1 * HALF_CHN + lane];
            unsigned h2 = Xh[(size_t)i2 * HALF_CHN + lane];
            unsigned h3 = Xh[(size_t)i3 * HALF_CHN + lane];
            unsigned h4 = Xh[(size_t)i4 * HALF_CHN + lane];
            unsigned h5 = Xh[(size_t)i5 * HALF_CHN + lane];
            unsigned h6 = Xh[(size_t)i6 * HALF_CHN + lane];
            unsigned h7 = Xh[(size_t)i7 * HALF_CHN + lane];
            float2 x0 = unpack_bf16x2(h0), x1 = unpack_bf16x2(h1);
            float2 x2 = unpack_bf16x2(h2), x3 = unpack_bf16x2(h3);
            float2 x4 = unpack_bf16x2(h4), x5 = unpack_bf16x2(h5);
            float2 x6 = unpack_bf16x2(h6), x7 = unpack_bf16x2(h7);
            a0.x += x0.x; a0.y += x0.y;  a1.x += x1.x; a1.y += x1.y;
            a2.x += x2.x; a2.y += x2.y;  a3.x += x3.x; a3.y += x3.y;
            a0.x += x4.x; a0.y += x4.y;  a1.x += x5.x; a1.y += x5.y;
            a2.x += x6.x; a2.y += x6.y;  a3.x += x7.x; a3.y += x7.y;
        }
        for (; k < deg; ++k) {
            float2 x = unpack_bf16x2(Xh[(size_t)bk[k] * HALF_CHN + lane]);
            a0.x += x.x; a0.y += x.y;
        }
        float2 acc;
        acc.x = (a0.x + a1.x) + (a2.x + a3.x);
        acc.y = (a0.y + a1.y) + (a2.y + a3.y);
        float2 y = ((const float2*)Y)[(size_t)edge * HALF_CHN + lane];
        float2 ef;
        ef.x = s0.x * acc.x + s1.x * y.x;
        ef.y = s0.y * acc.y + s1.y * y.y;
        ((float2*)edge_out)[(size_t)edge * HALF_CHN + lane] = ef;
        float we = (deg_raw > 0) ? 1.0f / (float)deg_raw : 0.0f;
        enh[(size_t)edge * HALF_CHN + lane] = pack_bf16x2(ef.x * we, ef.y * we);
    }
}

// ---------------------------------------------------------------------------
// 4) e2v fused: one block (512 thr = 8 waves) per 128-node bin. Node buckets
//    rebuilt in LDS from bins_v (no node_bkt global round-trip), then each
//    wave runs the proven unroll-8 gather over row-major enh.
// ---------------------------------------------------------------------------
__global__ __launch_bounds__(512) void e2v_fused_kernel(
    const unsigned* __restrict__ bins_v, const int* __restrict__ gcur_v,
    const float* __restrict__ X, const unsigned* __restrict__ enh,
    const float* __restrict__ lw,
    float* __restrict__ node_out, int n_nodes) {
    __shared__ int lcnt[BIN_W_V];
    __shared__ unsigned short nbkt[BIN_W_V][CAP_V];   // 128*48*2 = 12 KB
    int b = blockIdx.x;
    int lo = b << SH_V;
    int hi = lo + BIN_W_V; if (hi > n_nodes) hi = n_nodes;
    int nl = hi - lo;
    for (int i = threadIdx.x; i < nl; i += 512) lcnt[i] = 0;
    __syncthreads();
    int m = gcur_v[b];
    if (m > CAP_BIN_V) m = CAP_BIN_V;
    if (m < 0) m = 0;
    const unsigned* seg = bins_v + (size_t)b * CAP_BIN_V;
    for (int i = threadIdx.x; i < m; i += 512) {
        unsigned p = seg[i];
        int vl = (int)(p >> 16) & (BIN_W_V - 1);
        int e  = (int)(p & 0xFFFFu);
        int s = atomicAdd(&lcnt[vl], 1);
        if (s < CAP_V) nbkt[vl][s] = (unsigned short)e;
    }
    __syncthreads();

    int wv = threadIdx.x >> 6, lane = threadIdx.x & 63;
    float2 s0, s1;
    lane_softmax(lw, lane, s0, s1);

    for (int me = wv; me < nl; me += 8) {
        int node = lo + me;
        int deg = lcnt[me];                     // wave-uniform (LDS broadcast)
        if (deg > CAP_V) deg = CAP_V;
        const unsigned short* bk = nbkt[me];
        float2 a0 = {0.f,0.f}, a1 = {0.f,0.f}, a2 = {0.f,0.f}, a3 = {0.f,0.f};
        int k = 0;
        for (; k + 8 <= deg; k += 8) {
            int i0 = bk[k+0], i1 = bk[k+1], i2 = bk[k+2], i3 = bk[k+3];
            int i4 = bk[k+4], i5 = bk[k+5], i6 = bk[k+6], i7 = bk[k+7];
            unsigned h0 = enh[(size_t)i0 * HALF_CHN + lane];
            unsigned h1 = enh[(size_t)i1 * HALF_CHN + lane];
            unsigned h2 = enh[(size_t)i2 * HALF_CHN + lane];
            unsigned h3 = enh[(size_t)i3 * HALF_CHN + lane];
            unsigned h4 = enh[(size_t)i4 * HALF_CHN + lane];
            unsigned h5 = enh[(size_t)i5 * HALF_CHN + lane];
            unsigned h6 = enh[(size_t)i6 * HALF_CHN + lane];
            unsigned h7 = enh[(size_t)i7 * HALF_CHN + lane];
            float2 x0 = unpack_bf16x2(h0), x1 = unpack_bf16x2(h1);
            float2 x2 = unpack_bf16x2(h2), x3 = unpack_bf16x2(h3);
            float2 x4 = unpack_bf16x2(h4), x5 = unpack_bf16x2(h5);
            float2 x6 = unpack_bf16x2(h6), x7 = unpack_bf16x2(h7);
            a0.x += x0.x; a0.y += x0.y;  a1.x += x1.x; a1.y += x1.y;
            a2.x += x2.x; a2.y += x2.y;  a3.x += x3.x; a3.y += x3.y;
            a0.x += x4.x; a0.y += x4.y;  a1.x += x5.x; a1.y += x5.y;
            a2.x += x6.x; a2.y += x6.y;  a3.x += x7.x; a3.y += x7.y;
        }
        for (; k < deg; ++k) {
            float2 x = unpack_bf16x2(enh[(size_t)bk[k] * HALF_CHN + lane]);
            a0.x += x.x; a0.y += x.y;
        }
        float2 acc;
        acc.x = (a0.x + a1.x) + (a2.x + a3.x);
        acc.y = (a0.y + a1.y) + (a2.y + a3.y);
        float2 x = ((const float2*)X)[(size_t)node * HALF_CHN + lane];
        float2 nf;
        nf.x = s0.x * acc.x + s1.x * x.x;
        nf.y = s0.y * acc.y + s1.y * x.y;
        ((float2*)node_out)[(size_t)node * HALF_CHN + lane] = nf;
    }
}

// ---------------------------------------------------------------------------
extern "C" void kernel_launch(void* const* d_in, const int* in_sizes, int n_in,
                              void* d_out, int out_size, void* d_ws, size_t ws_size,
                              hipStream_t stream) {
    const float* X  = (const float*)d_in[0];
    const float* Y  = (const float*)d_in[1];
    const float* lw = (const float*)d_in[2];
    const int* node_idx = (const int*)d_in[3];
    const int* edge_idx = (const int*)d_in[4];

    const int N   = in_sizes[0] / CHN;   // 100000
    const int E   = in_sizes[1] / CHN;   // 50000
    const int nnz = in_sizes[3];         // 1600000

    float* node_out = (float*)d_out;                    // [N, C]  [0, 51.2 MB)
    float* edge_out = (float*)d_out + (size_t)N * CHN;  // [E, C]  [51.2, 76.8 MB)

    const int nbv = (N + BIN_W_V - 1) >> SH_V;    // 782
    const int nbe = (E + BIN_W_EF - 1) >> SH_EF;  // 782

    // d_out dead-region reuse:
    //   [0, 25.6 MB)      Xh : N*64 u32 bf16x2 rows (dead before e2v writes)
    //   [25.6, ~33.6 MB)  bins_e : u32 packed segments (dead after fill_e_v2e)
    unsigned* Xh     = (unsigned*)d_out;
    unsigned* bins_e = (unsigned*)((char*)d_out + (size_t)N * HALF_CHN * 4);

    // --- workspace carve-out (256B aligned), ~20.9 MB total ---
    char* p = (char*)d_ws;
    auto carve = [&](size_t bytes) {
        char* r = p;
        p += (bytes + 255) & ~(size_t)255;
        return r;
    };
    int* gcur   = (int*)carve((size_t)(2 * MAXB) * 4);
    int* gcur_v = gcur;
    int* gcur_e = gcur + MAXB;
    unsigned* bins_v = (unsigned*)carve((size_t)nbv * CAP_BIN_V * 4);  // 8.0 MB
    unsigned* enh    = (unsigned*)carve((size_t)E * HALF_CHN * 4);     // 12.8 MB
    (void)ws_size;

    // 1) zero bin cursors only (ws is poisoned before every call)
    hipMemsetAsync(gcur, 0, (size_t)(2 * MAXB) * 4, stream);

    // 2) partition into per-range u32 bins (block-aggregated reservations)
    {
        int nblk = (int)((nnz + B1_CHUNK - 1) / B1_CHUNK);
        partition_kernel<<<nblk, B1_THREADS, 0, stream>>>(
            node_idx, edge_idx, gcur_v, gcur_e, bins_v, bins_e, nnz, nbv, nbe);
    }

    // 3) count node degrees in LDS + cast Xh (no bucket stores, no cnt_v)
    count_v_cast_kernel<<<nbv, 512, 0, stream>>>(
        bins_v, gcur_v, (const float2*)X, Xh, N);

    // 4) fused fill_e + v2e (LDS buckets; row-major enh)
    fill_e_v2e_kernel<<<nbe, 512, 0, stream>>>(
        bins_e, gcur_e, Xh, Y, lw, edge_out, enh, E);

    // 5) fused e2v: LDS node buckets from bins_v + proven gather -> node_out
    e2v_fused_kernel<<<nbv, 512, 0, stream>>>(
        bins_v, gcur_v, X, enh, lw, node_out, N);
}